// Round 13
// baseline (212.297 us; speedup 1.0000x reference)
//
#include <hip/hip_runtime.h>

typedef __attribute__((ext_vector_type(8))) short s16x8;
typedef __attribute__((ext_vector_type(4))) float f32x4;

#define DEV static __device__ __forceinline__

DEV float b2f(unsigned short u){
  unsigned int i = ((unsigned int)u) << 16;
  float f; __builtin_memcpy(&f, &i, 4); return f;
}
DEV unsigned short f2b(float f){
  unsigned int i; __builtin_memcpy(&i, &f, 4);
  i = i + 0x7fffu + ((i >> 16) & 1u);
  return (unsigned short)(i >> 16);
}
DEV f32x4 mfma16(s16x8 a, s16x8 b, f32x4 c){
  return __builtin_amdgcn_mfma_f32_16x16x32_bf16(a, b, c, 0, 0, 0);
}
// load 8 consecutive f32 (32B-aligned) -> bf16 A/B fragment
DEV s16x8 ld8f(const float* p){
  const float4* q4 = (const float4*)p;
  float4 a = q4[0], b = q4[1];
  s16x8 r;
  r[0]=(short)f2b(a.x); r[1]=(short)f2b(a.y); r[2]=(short)f2b(a.z); r[3]=(short)f2b(a.w);
  r[4]=(short)f2b(b.x); r[5]=(short)f2b(b.y); r[6]=(short)f2b(b.z); r[7]=(short)f2b(b.w);
  return r;
}

// DPP-based 16-lane all-reduce (sum / max)
template<int C> DEV float dpp_addstep(float x){
  int y = __builtin_amdgcn_update_dpp(0, __builtin_bit_cast(int, x), C, 0xF, 0xF, true);
  return x + __builtin_bit_cast(float, y);
}
template<int C> DEV float dpp_maxstep(float x){
  int y = __builtin_amdgcn_update_dpp(0, __builtin_bit_cast(int, x), C, 0xF, 0xF, true);
  return fmaxf(x, __builtin_bit_cast(float, y));
}
DEV float rsum16(float v){
  v = dpp_addstep<0xB1>(v);
  v = dpp_addstep<0x4E>(v);
  v = dpp_addstep<0x141>(v);
  v = dpp_addstep<0x140>(v);
  return v;
}
DEV float rmax16(float v){
  v = dpp_maxstep<0xB1>(v);
  v = dpp_maxstep<0x4E>(v);
  v = dpp_maxstep<0x141>(v);
  v = dpp_maxstep<0x140>(v);
  return v;
}

// ---------------------------------------------------------------------------
// K0 (round-12): weight pack (blocks 0..59) + slot-init + qk2 precompute
// (blocks 60..75). qk2[b][slot][d] = bf16( q0[slot][h] . Wk[h][d] ) lets the
// fused it=0 attention compute scores = xn @ qk2^T directly from the LN'd x
// already in LDS (no k-tile). Rows 8..15 of each qk2 batch-tile are zero.
// wall layout (elements): wih@0 whh@12288 w1@24576 w2@32768 wq@40960.
// ---------------------------------------------------------------------------
__global__ __launch_bounds__(256) void k_wpack2(
    const float* __restrict__ Wk, const float* __restrict__ Wv,
    const float* __restrict__ wih, const float* __restrict__ whh,
    const float* __restrict__ w1, const float* __restrict__ w2,
    const float* __restrict__ Wq,
    unsigned short* __restrict__ wkb, unsigned short* __restrict__ wvb,
    unsigned short* __restrict__ wall,
    const float* __restrict__ noise,
    const float* __restrict__ mu,
    const float* __restrict__ lsg,
    const float* __restrict__ gsl,
    const float* __restrict__ bsl,
    float* __restrict__ slots,
    unsigned short* __restrict__ qws,
    unsigned short* __restrict__ qk2g)
{
  const int tid = threadIdx.x;
  if (blockIdx.x < 60){
    int t = blockIdx.x * 256 + tid;
    int off = t * 4;
    const float* src; unsigned short* dst;
    if      (off <  8192){ src = Wk  + off;         dst = wkb  + off; }
    else if (off < 16384){ src = Wv  + off -  8192; dst = wvb  + off - 8192; }
    else if (off < 28672){ src = wih + off - 16384; dst = wall + off - 16384; }
    else if (off < 40960){ src = whh + off - 28672; dst = wall + off - 16384; }
    else if (off < 49152){ src = w1  + off - 40960; dst = wall + off - 16384; }
    else if (off < 57344){ src = w2  + off - 49152; dst = wall + off - 16384; }
    else                 { src = Wq  + off - 57344; dst = wall + off - 16384; }
    float4 v = *(const float4*)src;
    ushort4 o;
    o.x = f2b(v.x); o.y = f2b(v.y); o.z = f2b(v.z); o.w = f2b(v.w);
    *(ushort4*)dst = o;
    return;
  }

  // ---------------- init path (16 blocks: 60..75) ----------------
  __shared__ unsigned short st[16*72];
  __shared__ unsigned short wkl[8192];         // Wk bf16 [64][128]
  __shared__ __align__(16) float redS[16][4];
  __shared__ __align__(16) float redQ[16][4];
  const int w = tid >> 6, ln = tid & 63;
  const int m16 = ln & 15, q = ln >> 4;
  const int bi = blockIdx.x - 60;
  const int r0 = bi * 16;
  const int cw = w*16 + m16;

  // stage Wk -> LDS bf16
  for (int i = tid; i < 2048; i += 256){
    float4 v = ((const float4*)Wk)[i];
    ushort4 o;
    o.x = f2b(v.x); o.y = f2b(v.y); o.z = f2b(v.z); o.w = f2b(v.w);
    ((ushort4*)wkl)[i] = o;
  }

  float sl[4], s1[4], s2[4];
  #pragma unroll
  for (int rr = 0; rr < 4; ++rr){
    int row = r0 + q*4 + rr;
    int k = row & 7;
    float v = mu[k*64 + cw] + (log1pf(expf(lsg[k*64 + cw])) + 1e-5f) * noise[row*64 + cw];
    sl[rr] = v;
    slots[row*64 + cw] = v;
    s1[rr] = rsum16(v);
    s2[rr] = rsum16(v*v);
  }
  if (m16 == 0){
    #pragma unroll
    for (int rr = 0; rr < 4; ++rr){ redS[q*4+rr][w] = s1[rr]; redQ[q*4+rr][w] = s2[rr]; }
  }
  __syncthreads();
  {
    const float gs = gsl[cw], bs = bsl[cw];
    #pragma unroll
    for (int rr = 0; rr < 4; ++rr){
      f32x4 aS = *(const f32x4*)redS[q*4+rr];
      f32x4 aQ = *(const f32x4*)redQ[q*4+rr];
      float tS = aS[0]+aS[1]+aS[2]+aS[3];
      float tQ = aQ[0]+aQ[1]+aQ[2]+aQ[3];
      float mean = tS*(1.f/64.f);
      float var  = tQ*(1.f/64.f) - mean*mean;
      float rs = rsqrtf(var + 1e-5f);
      float sq = (sl[rr] - mean)*rs*gs + bs;
      st[(q*4+rr)*72 + cw] = f2b(sq);
    }
  }
  __syncthreads();
  unsigned short qv[4];
  {
    f32x4 acc = {0,0,0,0};
    #pragma unroll
    for (int ks = 0; ks < 2; ++ks){
      s16x8 a = *(const s16x8*)(st + m16*72 + ks*32 + q*8);
      acc = mfma16(a, ld8f(Wq + cw*64 + ks*32 + q*8), acc);
    }
    #pragma unroll
    for (int rr = 0; rr < 4; ++rr){
      int row = r0 + q*4 + rr;
      int bb_ = row >> 3, kk = row & 7;
      qv[rr] = f2b(acc[rr] * 0.125f);
      qws[(bb_*16 + kk)*64 + cw] = qv[rr];
    }
    int b0 = bi * 2;
    ((unsigned int*)(qws + (b0*16 + 8)*64))[tid] = 0u;
    ((unsigned int*)(qws + ((b0+1)*16 + 8)*64))[tid] = 0u;
  }
  __syncthreads();                 // all st reads done
  #pragma unroll
  for (int rr = 0; rr < 4; ++rr)
    st[(q*4+rr)*72 + cw] = qv[rr]; // st now holds q bf16 (local rows 0..15)
  __syncthreads();

  // qk2[lb2][slot][d] = sum_h q[slot][h] * Wk_bf16[h][d]
  for (int idx = tid; idx < 2048; idx += 256){
    int lb2  = idx >> 10;
    int rem  = idx & 1023;
    int slot = rem >> 7;
    int d    = rem & 127;
    int srow = lb2*8 + slot;
    float s = 0.f;
    #pragma unroll
    for (int h = 0; h < 64; ++h)
      s += b2f(st[srow*72 + h]) * b2f(wkl[h*128 + d]);
    qk2g[(((bi*2 + lb2)*16) + slot)*128 + d] = f2b(s);
  }
  // zero pad rows (slots 8..15)
  for (int i = tid; i < 512; i += 256){
    ((unsigned int*)(qk2g + ((bi*2    )*16 + 8)*128))[i] = 0u;
    ((unsigned int*)(qk2g + ((bi*2 + 1)*16 + 8)*128))[i] = 0u;
  }
}

// ---------------------------------------------------------------------------
// K1 (round-12): LN(x) -> kg, vt (FROZEN store schedule) + FUSED it=0
// attention on this block's 128 rows. The fused phase runs strictly AFTER
// the kg/vt stores (write-merge invariant intact) and overlays vtile/aT
// into the then-dead xs region (LDS unchanged -> 4 blocks/CU).
// Produces 32 U/S partials per batch (128-row granularity).
// ---------------------------------------------------------------------------
__global__ __launch_bounds__(256, 4) void k_lnkv8(
    const float* __restrict__ x,
    const unsigned short* __restrict__ wkb,
    const unsigned short* __restrict__ wvb,
    const float* __restrict__ lg,
    const float* __restrict__ lb,
    unsigned short* __restrict__ kg,
    unsigned short* __restrict__ vt,
    const unsigned short* __restrict__ qk2g,
    float* __restrict__ Up0, float* __restrict__ Sp0)
{
  __shared__ __align__(16) unsigned int xs[128 * 68];
  const int tid = threadIdx.x;
  const int w = tid >> 6, ln = tid & 63;
  const int m16 = ln & 15, q = ln >> 4;

  const int b = blockIdx.x >> 5;
  const int t128 = blockIdx.x & 31;
  const int nbase = t128 << 7;
  const long rowg0 = (long)b * 4096 + nbase;

  // phase 1: LN(x) -> LDS bf16 (frozen)
  {
    const int c = m16;
    const float4 gA = *(const float4*)(lg + c*4);
    const float4 gB = *(const float4*)(lg + 64 + c*4);
    const float4 bA = *(const float4*)(lb + c*4);
    const float4 bB = *(const float4*)(lb + 64 + c*4);
    const float* base = x + (rowg0 + w*32 + q)*128;

    float4 va[4], vb[4];
    #pragma unroll
    for (int i = 0; i < 3; ++i){
      va[i] = *(const float4*)(base + i*512 + c*4);
      vb[i] = *(const float4*)(base + i*512 + 64 + c*4);
    }
    #pragma unroll
    for (int p = 0; p < 8; ++p){
      const int cur = p & 3;
      if (p < 5){
        const int nxt = (p+3) & 3;
        va[nxt] = *(const float4*)(base + (p+3)*512 + c*4);
        vb[nxt] = *(const float4*)(base + (p+3)*512 + 64 + c*4);
      }
      float4 u = va[cur], t = vb[cur];
      float s1 = (u.x + u.y) + (u.z + u.w) + (t.x + t.y) + (t.z + t.w);
      float s2 = (u.x*u.x + u.y*u.y) + (u.z*u.z + u.w*u.w)
               + (t.x*t.x + t.y*t.y) + (t.z*t.z + t.w*t.w);
      s1 = rsum16(s1);
      s2 = rsum16(s2);
      float mean = s1 * (1.f/128.f);
      float var  = s2 * (1.f/128.f) - mean*mean;
      float rs = rsqrtf(var + 1e-5f);
      float y0 = (u.x - mean)*rs*gA.x + bA.x;
      float y1 = (u.y - mean)*rs*gA.y + bA.y;
      float y2 = (u.z - mean)*rs*gA.z + bA.z;
      float y3 = (u.w - mean)*rs*gA.w + bA.w;
      float y4 = (t.x - mean)*rs*gB.x + bB.x;
      float y5 = (t.y - mean)*rs*gB.y + bB.y;
      float y6 = (t.z - mean)*rs*gB.z + bB.z;
      float y7 = (t.w - mean)*rs*gB.w + bB.w;
      uint2 pkA, pkB;
      pkA.x = (unsigned int)f2b(y0) | ((unsigned int)f2b(y1) << 16);
      pkA.y = (unsigned int)f2b(y2) | ((unsigned int)f2b(y3) << 16);
      pkB.x = (unsigned int)f2b(y4) | ((unsigned int)f2b(y5) << 16);
      pkB.y = (unsigned int)f2b(y6) | ((unsigned int)f2b(y7) << 16);
      const int r = w*32 + p*4 + q;
      *(uint2*)&xs[r*68 + c*2] = pkA;
      *(uint2*)&xs[r*68 + 32 + c*2] = pkB;
    }
  }

  s16x8 bw[4][4];
  #pragma unroll
  for (int t = 0; t < 4; ++t)
    #pragma unroll
    for (int kb = 0; kb < 4; ++kb)
      bw[kb][t] = *(const s16x8*)(wkb + (t*16 + m16)*128 + kb*32 + q*8);

  __syncthreads();

  const f32x4 zf = {0.f, 0.f, 0.f, 0.f};

  // kg (per-row lines covered by one wave -> safe)
  #pragma unroll
  for (int mi = 0; mi < 2; ++mi){
    int n0 = (w*2 + mi) * 16;
    f32x4 acc[4];
    #pragma unroll
    for (int t = 0; t < 4; ++t) acc[t] = zf;
    #pragma unroll
    for (int kb = 0; kb < 4; ++kb){
      s16x8 af = *(const s16x8*)((const unsigned short*)(xs + (n0 + m16)*68) + kb*32 + q*8);
      #pragma unroll
      for (int t = 0; t < 4; ++t)
        acc[t] = mfma16(af, bw[kb][t], acc[t]);
    }
    #pragma unroll
    for (int t = 0; t < 4; ++t){
      int h = t*16 + m16;
      #pragma unroll
      for (int rr = 0; rr < 4; ++rr){
        long n = rowg0 + n0 + q*4 + rr;
        kg[n*64 + h] = f2b(acc[t][rr]);
      }
    }
  }

  #pragma unroll
  for (int t = 0; t < 4; ++t)
    #pragma unroll
    for (int kb = 0; kb < 4; ++kb)
      bw[kb][t] = *(const s16x8*)(wvb + (t*16 + m16)*128 + kb*32 + q*8);

  // vt: keep accumulators (accV) for the fused phase; store schedule frozen
  f32x4 accV[2][4];
  #pragma unroll
  for (int mi = 0; mi < 2; ++mi){
    #pragma unroll
    for (int t = 0; t < 4; ++t) accV[mi][t] = zf;
    #pragma unroll
    for (int kb = 0; kb < 4; ++kb){
      int n0 = (w*2 + mi) * 16;
      s16x8 af = *(const s16x8*)((const unsigned short*)(xs + (n0 + m16)*68) + kb*32 + q*8);
      #pragma unroll
      for (int t = 0; t < 4; ++t)
        accV[mi][t] = mfma16(af, bw[kb][t], accV[mi][t]);
    }
    int n0 = (w*2 + mi) * 16;
    #pragma unroll
    for (int t = 0; t < 4; ++t){
      int h = t*16 + m16;
      unsigned int p0 = (unsigned int)f2b(accV[mi][t][0]) | ((unsigned int)f2b(accV[mi][t][1]) << 16);
      unsigned int p1 = (unsigned int)f2b(accV[mi][t][2]) | ((unsigned int)f2b(accV[mi][t][3]) << 16);
      uint2 pv; pv.x = p0; pv.y = p1;
      long off = ((long)b*64 + h)*4096 + nbase + n0 + q*4;
      *(uint2*)(vt + off) = pv;
    }
  }

  // ---- fused it=0 attention (after stores; reads xs one last time) ----
  // scores = xn @ qk2^T  (A from xs, B from qk2g; pad slots give 0)
  s16x8 bqk[4];
  #pragma unroll
  for (int kb = 0; kb < 4; ++kb)
    bqk[kb] = *(const s16x8*)(qk2g + ((long)b*16 + m16)*128 + kb*32 + q*8);

  f32x4 accS[2];
  #pragma unroll
  for (int mi = 0; mi < 2; ++mi){
    accS[mi] = zf;
    int n0 = (w*2 + mi) * 16;
    #pragma unroll
    for (int kb = 0; kb < 4; ++kb){
      s16x8 af = *(const s16x8*)((const unsigned short*)(xs + (n0 + m16)*68) + kb*32 + q*8);
      accS[mi] = mfma16(af, bqk[kb], accS[mi]);
    }
  }
  __syncthreads();                 // all xs reads complete -> xs reusable

  // overlay: vtile [64][136]u16 @0, aT [16][136]u16 @17408B, redPS @21760B
  unsigned short* vtile = (unsigned short*)xs;
  unsigned short* aTl   = (unsigned short*)xs + 8704;
  float (*redPS)[4]     = (float(*)[4])((char*)xs + 21760);

  for (int i = tid; i < 1088; i += 256) ((unsigned int*)aTl)[i] = 0u;
  __syncthreads();

  // vtile from accV (bf16 identical to global vt values)
  #pragma unroll
  for (int mi = 0; mi < 2; ++mi){
    int n0 = (w*2 + mi) * 16;
    #pragma unroll
    for (int t = 0; t < 4; ++t){
      unsigned int p0 = (unsigned int)f2b(accV[mi][t][0]) | ((unsigned int)f2b(accV[mi][t][1]) << 16);
      unsigned int p1 = (unsigned int)f2b(accV[mi][t][2]) | ((unsigned int)f2b(accV[mi][t][3]) << 16);
      uint2 pv; pv.x = p0; pv.y = p1;
      *(uint2*)(vtile + (t*16 + m16)*136 + n0 + q*4) = pv;
    }
  }

  // in-register softmax (per row; slots live in lanes m16 0..7)
  float s_loc = 0.f;
  #pragma unroll
  for (int mi = 0; mi < 2; ++mi){
    int n0 = (w*2 + mi) * 16;
    unsigned short av[4];
    #pragma unroll
    for (int rr = 0; rr < 4; ++rr){
      float vm = (m16 < 8) ? accS[mi][rr] : -1e30f;
      float mx = rmax16(vm);
      float e  = (m16 < 8) ? expf(accS[mi][rr] - mx) : 0.f;
      float ss = rsum16(e);
      float a  = e * (1.f/ss) + 1e-8f;
      av[rr] = f2b(a);
      if (m16 < 8) s_loc += b2f(av[rr]);
    }
    if (m16 < 8){
      unsigned int p0 = (unsigned int)av[0] | ((unsigned int)av[1] << 16);
      unsigned int p1 = (unsigned int)av[2] | ((unsigned int)av[3] << 16);
      uint2 pv; pv.x = p0; pv.y = p1;
      *(uint2*)(aTl + m16*136 + n0 + q*4) = pv;
    }
  }
  // S partials: reduce rows over q (xor16, xor32) then over waves via LDS
  s_loc += __shfl_xor(s_loc, 16);
  s_loc += __shfl_xor(s_loc, 32);
  if (q == 0 && m16 < 8) redPS[m16][w] = s_loc;
  __syncthreads();
  if (tid < 8){
    f32x4 r = *(const f32x4*)redPS[tid];
    Sp0[((long)b*32 + t128)*8 + tid] = r[0]+r[1]+r[2]+r[3];
  }

  // U partials: aT (A) x vtile (B); wave w -> h block w*16
  {
    f32x4 accU = zf;
    #pragma unroll
    for (int ks = 0; ks < 4; ++ks){
      s16x8 afA = *(const s16x8*)(aTl + m16*136 + ks*32 + q*8);
      s16x8 bfV = *(const s16x8*)(vtile + (w*16 + m16)*136 + ks*32 + q*8);
      accU = mfma16(afA, bfV, accU);
    }
    float* ub = Up0 + (((long)b*32 + t128)*8)*64 + w*16 + m16;
    #pragma unroll
    for (int rr = 0; rr < 4; ++rr){
      int slot = q*4 + rr;
      if (slot < 8)
        ub[slot*64] = accU[rr];
    }
  }
}

// ---------------------------------------------------------------------------
// K3: [GRU prologue (sums npart U/S partials)] + attention. Body = verified
// round-7/11 k_attn3 (XCD swizzle kept) + npart parameterization (32 for
// it=1 reading the fused it=0 partials, 16 for it=2).
// ---------------------------------------------------------------------------
__global__ __launch_bounds__(256) void k_attn3(
    const unsigned short* __restrict__ kg,
    const unsigned short* __restrict__ vt,
    const unsigned short* __restrict__ wall,  // packed [wih|whh|w1|w2|wq] bf16
    const float* __restrict__ bih, const float* __restrict__ bhh,
    const float* __restrict__ b1p, const float* __restrict__ b2p,
    const float* __restrict__ gmlp, const float* __restrict__ bmlp,
    const float* __restrict__ gsl, const float* __restrict__ bsl,
    const float* __restrict__ Up_in, const float* __restrict__ Sp_in,
    float* __restrict__ Up_out, float* __restrict__ Sp_out,
    const float* __restrict__ slin, float* __restrict__ slout,
    int npart)
{
  __shared__ float sc[256*17];
  __shared__ unsigned short aT[16*264];
  __shared__ unsigned short ut[16*72], ht[16*72], st[16*72], hid[16*136];
  __shared__ unsigned short qloc[16*72];
  __shared__ __align__(16) float redS[16][4];
  __shared__ __align__(16) float redQ[16][4];
  __shared__ __align__(16) float redS2[16][4];
  __shared__ __align__(16) float redQ2[16][4];

  const int tid = threadIdx.x;
  const int w = tid >> 6, ln = tid & 63;
  const int m16 = ln & 15, q = ln >> 4;

  const int p_   = blockIdx.x;
  const int xcd  = p_ & 7;
  const int slot = p_ >> 3;
  const int lb   = ((xcd << 1) + (slot >> 5))*32 + (slot & 31);
  const int b = lb >> 4;
  const int tile = lb & 15;
  const int nbase = tile << 8;

  // prefetch attention operands
  s16x8 afp[4], afp2[4];
  #pragma unroll
  for (int mi = 0; mi < 4; ++mi){
    int n0 = (w*4 + mi)*16;
    afp[mi]  = *(const s16x8*)(kg + ((long)b*4096 + nbase + n0 + m16)*64 + q*8);
    afp2[mi] = *(const s16x8*)(kg + ((long)b*4096 + nbase + n0 + m16)*64 + 32 + q*8);
  }
  s16x8 vtp[8];
  #pragma unroll
  for (int ks = 0; ks < 8; ++ks)
    vtp[ks] = *(const s16x8*)(vt + ((long)b*64 + w*16 + m16)*4096 + nbase + ks*32 + q*8);

  for (int i = tid; i < 8*264; i += 256) aT[8*264 + i] = 0;
  if (tid < 128){
    int row = 8 + (tid >> 4), c = (tid & 15)*4;
    ushort4 z4 = {0,0,0,0};
    *(ushort4*)&qloc[row*72 + c] = z4;
  }

  {
    // ---- redundant GRU+LN+MLP+LN_sl+q for batch pair (b&~1, b|1) ----
    const int r0 = (b >> 1) * 16;
    const int cw = w*16 + m16;
    const unsigned short* wihb = wall;
    const unsigned short* whhb = wall + 12288;
    const unsigned short* w1b  = wall + 24576;
    const unsigned short* w2b  = wall + 32768;
    const unsigned short* wqb  = wall + 40960;

    #pragma unroll
    for (int p = 0; p < 4; ++p){
      int row = p*4 + w;
      int g = r0 + row;
      int bb = g >> 3, sl = g & 7;
      const float* up  = Up_in + ((long)(bb*npart)*8 + sl)*64 + ln;
      const float* spp = Sp_in + (long)(bb*npart)*8 + sl;
      float usum = 0.f, ssum = 0.f;
      if (npart == 32){
        #pragma unroll
        for (int t = 0; t < 32; ++t){ usum += up[t*512]; ssum += spp[t*8]; }
      } else {
        #pragma unroll
        for (int t = 0; t < 16; ++t){ usum += up[t*512]; ssum += spp[t*8]; }
      }
      ut[row*72 + ln] = f2b(usum / ssum);
      ht[row*72 + ln] = f2b(slin[g*64 + ln]);
    }
    __syncthreads();

    f32x4 axr = {0,0,0,0}, axz = {0,0,0,0}, axn = {0,0,0,0};
    f32x4 ahr = {0,0,0,0}, ahz = {0,0,0,0}, ahn = {0,0,0,0};
    #pragma unroll
    for (int ks = 0; ks < 2; ++ks){
      s16x8 au = *(const s16x8*)(ut + m16*72 + ks*32 + q*8);
      s16x8 ah = *(const s16x8*)(ht + m16*72 + ks*32 + q*8);
      axr = mfma16(au, *(const s16x8*)(wihb + (      cw)*64 + ks*32 + q*8), axr);
      axz = mfma16(au, *(const s16x8*)(wihb + ( 64 + cw)*64 + ks*32 + q*8), axz);
      axn = mfma16(au, *(const s16x8*)(wihb + (128 + cw)*64 + ks*32 + q*8), axn);
      ahr = mfma16(ah, *(const s16x8*)(whhb + (      cw)*64 + ks*32 + q*8), ahr);
      ahz = mfma16(ah, *(const s16x8*)(whhb + ( 64 + cw)*64 + ks*32 + q*8), ahz);
      ahn = mfma16(ah, *(const s16x8*)(whhb + (128 + cw)*64 + ks*32 + q*8), ahn);
    }
    const float bxr = bih[cw], bxz = bih[64+cw], bxn = bih[128+cw];
    const float bhr = bhh[cw], bhz = bhh[64+cw], bhn = bhh[128+cw];
    float sp[4];
    #pragma unroll
    for (int rr = 0; rr < 4; ++rr){
      float xr = axr[rr] + bxr, xz = axz[rr] + bxz, xnv = axn[rr] + bxn;
      float hr = ahr[rr] + bhr, hz = ahz[rr] + bhz, hn = ahn[rr] + bhn;
      float rg = 1.f / (1.f + expf(-(xr + hr)));
      float zg = 1.f / (1.f + expf(-(xz + hz)));
      float ng = tanhf(xnv + rg*hn);
      float hv = b2f(ht[(q*4 + rr)*72 + cw]);
      sp[rr] = (1.f - zg)*ng + zg*hv;
    }

    float s1[4], s2[4];
    #pragma unroll
    for (int rr = 0; rr < 4; ++rr){
      s1[rr] = rsum16(sp[rr]);
      s2[rr] = rsum16(sp[rr]*sp[rr]);
    }
    if (m16 == 0){
      #pragma unroll
      for (int rr = 0; rr < 4; ++rr){ redS[q*4+rr][w] = s1[rr]; redQ[q*4+rr][w] = s2[rr]; }
    }
    __syncthreads();
    float sl_[4];
    {
      const float gm = gmlp[cw], bm = bmlp[cw];
      #pragma unroll
      for (int rr = 0; rr < 4; ++rr){
        f32x4 aS = *(const f32x4*)redS[q*4+rr];
        f32x4 aQ = *(const f32x4*)redQ[q*4+rr];
        float tS = aS[0]+aS[1]+aS[2]+aS[3];
        float tQ = aQ[0]+aQ[1]+aQ[2]+aQ[3];
        float mean = tS*(1.f/64.f);
        float var  = tQ*(1.f/64.f) - mean*mean;
        float rs = rsqrtf(var + 1e-5f);
        sl_[rr] = (sp[rr] - mean)*rs*gm + bm;
        st[(q*4+rr)*72 + cw] = f2b(sl_[rr]);
      }
    }
    __syncthreads();

    #pragma unroll
    for (int t2 = 0; t2 < 2; ++t2){
      int nt = w*2 + t2;
      int col = nt*16 + m16;
      f32x4 acc = {0,0,0,0};
      #pragma unroll
      for (int ks = 0; ks < 2; ++ks){
        s16x8 a = *(const s16x8*)(st + m16*72 + ks*32 + q*8);
        acc = mfma16(a, *(const s16x8*)(w1b + col*64 + ks*32 + q*8), acc);
      }
      float bb = b1p[col];
      #pragma unroll
      for (int rr = 0; rr < 4; ++rr)
        hid[(q*4+rr)*136 + col] = f2b(fmaxf(acc[rr] + bb, 0.f));
    }
    __syncthreads();

    float snew[4];
    {
      f32x4 acc = {0,0,0,0};
      #pragma unroll
      for (int ks = 0; ks < 4; ++ks){
        s16x8 a = *(const s16x8*)(hid + m16*136 + ks*32 + q*8);
        acc = mfma16(a, *(const s16x8*)(w2b + cw*128 + ks*32 + q*8), acc);
      }
      float bb = b2p[cw];
      #pragma unroll
      for (int rr = 0; rr < 4; ++rr){
        snew[rr] = sl_[rr] + acc[rr] + bb;
        if ((lb & 31) == 0)
          slout[(r0 + q*4 + rr)*64 + cw] = snew[rr];
      }
    }

    #pragma unroll
    for (int rr = 0; rr < 4; ++rr){
      s1[rr] = rsum16(snew[rr]);
      s2[rr] = rsum16(snew[rr]*snew[rr]);
    }
    if (m16 == 0){
      #pragma unroll
      for (int rr = 0; rr < 4; ++rr){ redS2[q*4+rr][w] = s1[rr]; redQ2[q*4+rr][w] = s2[rr]; }
    }
    __syncthreads();
    {
      const float gs = gsl[cw], bs = bsl[cw];
      #pragma unroll
      for (int rr = 0; rr < 4; ++rr){
        f32x4 aS = *(const f32x4*)redS2[q*4+rr];
        f32x4 aQ = *(const f32x4*)redQ2[q*4+rr];
        float tS = aS[0]+aS[1]+aS[2]+aS[3];
        float tQ = aQ[0]+aQ[1]+aQ[2]+aQ[3];
        float mean = tS*(1.f/64.f);
        float var  = tQ*(1.f/64.f) - mean*mean;
        float rs = rsqrtf(var + 1e-5f);
        float sq = (snew[rr] - mean)*rs*gs + bs;
        st[(q*4+rr)*72 + cw] = f2b(sq);
      }
    }
    __syncthreads();
    {
      f32x4 acc = {0,0,0,0};
      #pragma unroll
      for (int ks = 0; ks < 2; ++ks){
        s16x8 a = *(const s16x8*)(st + m16*72 + ks*32 + q*8);
        acc = mfma16(a, *(const s16x8*)(wqb + cw*64 + ks*32 + q*8), acc);
      }
      #pragma unroll
      for (int rr = 0; rr < 4; ++rr){
        int rloc = q*4 + rr;
        if ((rloc >> 3) == (b & 1))
          qloc[(rloc & 7)*72 + cw] = f2b(acc[rr] * 0.125f);
      }
    }
  }
  __syncthreads();

  // ---- attention ----
  s16x8 bq[2];
  #pragma unroll
  for (int ks = 0; ks < 2; ++ks)
    bq[ks] = *(const s16x8*)(qloc + m16*72 + ks*32 + q*8);

  #pragma unroll
  for (int mi = 0; mi < 4; ++mi){
    int n0 = (w*4 + mi)*16;
    f32x4 acc = {0.f, 0.f, 0.f, 0.f};
    acc = mfma16(afp[mi],  bq[0], acc);
    acc = mfma16(afp2[mi], bq[1], acc);
    #pragma unroll
    for (int rr = 0; rr < 4; ++rr)
      sc[(n0 + q*4 + rr)*17 + m16] = acc[rr];
  }
  __syncthreads();

  {
    int r = tid;
    float a8[8];
    float mx = -1e30f;
    #pragma unroll
    for (int j = 0; j < 8; ++j){ a8[j] = sc[r*17 + j]; mx = fmaxf(mx, a8[j]); }
    float ssum = 0.f;
    #pragma unroll
    for (int j = 0; j < 8; ++j){ a8[j] = expf(a8[j] - mx); ssum += a8[j]; }
    float inv = 1.f/ssum;
    #pragma unroll
    for (int j = 0; j < 8; ++j)
      aT[j*264 + r] = f2b(a8[j]*inv + 1e-8f);
  }
  __syncthreads();

  {
    int j = tid >> 5, c = tid & 31;
    float p = 0.f;
    #pragma unroll
    for (int i = 0; i < 8; ++i) p += b2f(aT[j*264 + c + 32*i]);
    p = rsum16(p);
    p += __shfl_xor(p, 16);
    if ((tid & 31) == 0) Sp_out[((long)b*16 + tile)*8 + j] = p;
  }

  {
    f32x4 acc = {0.f, 0.f, 0.f, 0.f};
    #pragma unroll
    for (int ks = 0; ks < 8; ++ks){
      s16x8 af = *(const s16x8*)(aT + m16*264 + ks*32 + q*8);
      acc = mfma16(af, vtp[ks], acc);
    }
    float* ub = Up_out + (((long)b*16 + tile)*8)*64 + w*16 + m16;
    #pragma unroll
    for (int rr = 0; rr < 4; ++rr){
      int slot2 = q*4 + rr;
      if (slot2 < 8)
        ub[slot2*64] = acc[rr];
    }
  }
}

// ---------------------------------------------------------------------------
// K4: final GRU + LN_mlp + MLP(+residual) -> outp; sums 16 tile-partials.
// UNCHANGED.
// ---------------------------------------------------------------------------
__global__ __launch_bounds__(256) void k_gru2(
    const float* __restrict__ Up, const float* __restrict__ Sp,
    const float* __restrict__ slots,
    const float* __restrict__ wih, const float* __restrict__ whh,
    const float* __restrict__ bih, const float* __restrict__ bhh,
    const float* __restrict__ w1, const float* __restrict__ b1p,
    const float* __restrict__ w2, const float* __restrict__ b2p,
    const float* __restrict__ gmlp, const float* __restrict__ bmlp,
    float* __restrict__ outp)
{
  __shared__ unsigned short ut[16*72], ht[16*72], st[16*72], hid[16*136];
  __shared__ __align__(16) float redS[16][4];
  __shared__ __align__(16) float redQ[16][4];
  const int tid = threadIdx.x;
  const int w = tid >> 6, ln = tid & 63;
  const int m16 = ln & 15, q = ln >> 4;
  const int r0 = blockIdx.x * 16;
  const int cw = w*16 + m16;

  #pragma unroll
  for (int p = 0; p < 4; ++p){
    int row = p*4 + w;
    int g = r0 + row;
    int bb = g >> 3, sl = g & 7;
    const float* up  = Up + ((bb*16)*8 + sl)*64 + ln;
    const float* spp = Sp + (bb*16)*8 + sl;
    float usum = 0.f, ssum = 0.f;
    #pragma unroll
    for (int t = 0; t < 16; ++t){
      usum += up[t*512];
      ssum += spp[t*8];
    }
    ut[row*72 + ln] = f2b(usum / ssum);
    ht[row*72 + ln] = f2b(slots[g*64 + ln]);
  }
  __syncthreads();

  f32x4 axr = {0,0,0,0}, axz = {0,0,0,0}, axn = {0,0,0,0};
  f32x4 ahr = {0,0,0,0}, ahz = {0,0,0,0}, ahn = {0,0,0,0};
  #pragma unroll
  for (int ks = 0; ks < 2; ++ks){
    s16x8 au = *(const s16x8*)(ut + m16*72 + ks*32 + q*8);
    s16x8 ah = *(const s16x8*)(ht + m16*72 + ks*32 + q*8);
    axr = mfma16(au, ld8f(wih + (      cw)*64 + ks*32 + q*8), axr);
    axz = mfma16(au, ld8f(wih + ( 64 + cw)*64 + ks*32 + q*8), axz);
    axn = mfma16(au, ld8f(wih + (128 + cw)*64 + ks*32 + q*8), axn);
    ahr = mfma16(ah, ld8f(whh + (      cw)*64 + ks*32 + q*8), ahr);
    ahz = mfma16(ah, ld8f(whh + ( 64 + cw)*64 + ks*32 + q*8), ahz);
    ahn = mfma16(ah, ld8f(whh + (128 + cw)*64 + ks*32 + q*8), ahn);
  }
  const float bxr = bih[cw], bxz = bih[64+cw], bxn = bih[128+cw];
  const float bhr = bhh[cw], bhz = bhh[64+cw], bhn = bhh[128+cw];
  float sp[4];
  #pragma unroll
  for (int rr = 0; rr < 4; ++rr){
    float xr = axr[rr] + bxr, xz = axz[rr] + bxz, xnv = axn[rr] + bxn;
    float hr = ahr[rr] + bhr, hz = ahz[rr] + bhz, hn = ahn[rr] + bhn;
    float rg = 1.f / (1.f + expf(-(xr + hr)));
    float zg = 1.f / (1.f + expf(-(xz + hz)));
    float ng = tanhf(xnv + rg*hn);
    float hv = b2f(ht[(q*4 + rr)*72 + cw]);
    sp[rr] = (1.f - zg)*ng + zg*hv;
  }

  float s1[4], s2[4];
  #pragma unroll
  for (int rr = 0; rr < 4; ++rr){
    s1[rr] = rsum16(sp[rr]);
    s2[rr] = rsum16(sp[rr]*sp[rr]);
  }
  if (m16 == 0){
    #pragma unroll
    for (int rr = 0; rr < 4; ++rr){ redS[q*4+rr][w] = s1[rr]; redQ[q*4+rr][w] = s2[rr]; }
  }
  __syncthreads();
  float sl_[4];
  {
    const float gm = gmlp[cw], bm = bmlp[cw];
    #pragma unroll
    for (int rr = 0; rr < 4; ++rr){
      f32x4 aS = *(const f32x4*)redS[q*4+rr];
      f32x4 aQ = *(const f32x4*)redQ[q*4+rr];
      float tS = aS[0]+aS[1]+aS[2]+aS[3];
      float tQ = aQ[0]+aQ[1]+aQ[2]+aQ[3];
      float mean = tS*(1.f/64.f);
      float var  = tQ*(1.f/64.f) - mean*mean;
      float rs = rsqrtf(var + 1e-5f);
      sl_[rr] = (sp[rr] - mean)*rs*gm + bm;
      st[(q*4+rr)*72 + cw] = f2b(sl_[rr]);
    }
  }
  __syncthreads();

  #pragma unroll
  for (int t2 = 0; t2 < 2; ++t2){
    int nt = w*2 + t2;
    int col = nt*16 + m16;
    f32x4 acc = {0,0,0,0};
    #pragma unroll
    for (int ks = 0; ks < 2; ++ks){
      s16x8 a = *(const s16x8*)(st + m16*72 + ks*32 + q*8);
      acc = mfma16(a, ld8f(w1 + col*64 + ks*32 + q*8), acc);
    }
    float bb = b1p[col];
    #pragma unroll
    for (int rr = 0; rr < 4; ++rr)
      hid[(q*4+rr)*136 + col] = f2b(fmaxf(acc[rr] + bb, 0.f));
  }
  __syncthreads();

  {
    f32x4 acc = {0,0,0,0};
    #pragma unroll
    for (int ks = 0; ks < 4; ++ks){
      s16x8 a = *(const s16x8*)(hid + m16*136 + ks*32 + q*8);
      acc = mfma16(a, ld8f(w2 + cw*128 + ks*32 + q*8), acc);
    }
    float bb = b2p[cw];
    #pragma unroll
    for (int rr = 0; rr < 4; ++rr){
      int row = r0 + q*4 + rr;
      outp[row*64 + cw] = sl_[rr] + acc[rr] + bb;
    }
  }
}

// ---------------------------------------------------------------------------
extern "C" void kernel_launch(void* const* d_in, const int* in_sizes, int n_in,
                              void* d_out, int out_size, void* d_ws, size_t ws_size,
                              hipStream_t stream)
{
  const float* x    = (const float*)d_in[0];
  const float* noise= (const float*)d_in[1];
  const float* Wq   = (const float*)d_in[2];
  const float* Wk   = (const float*)d_in[3];
  const float* Wv   = (const float*)d_in[4];
  const float* ling = (const float*)d_in[5];
  const float* linb = (const float*)d_in[6];
  const float* gsl  = (const float*)d_in[7];
  const float* bsl  = (const float*)d_in[8];
  const float* gmlp = (const float*)d_in[9];
  const float* bmlp = (const float*)d_in[10];
  const float* wih  = (const float*)d_in[11];
  const float* whh  = (const float*)d_in[12];
  const float* bih  = (const float*)d_in[13];
  const float* bhh  = (const float*)d_in[14];
  const float* w1   = (const float*)d_in[15];
  const float* b1p  = (const float*)d_in[16];
  const float* w2   = (const float*)d_in[17];
  const float* b2p  = (const float*)d_in[18];
  const float* mu   = (const float*)d_in[19];
  const float* lsg  = (const float*)d_in[20];

  char* ws = (char*)d_ws;
  unsigned short* kg   = (unsigned short*)(ws);              // 16 MiB
  unsigned short* vt   = (unsigned short*)(ws + 16777216);   // 16 MiB
  char* base = ws + 33554432;
  unsigned short* qws  = (unsigned short*)(base);            // 64 KiB
  float* slotsA        = (float*)(base + 65536);
  float* slotsB        = (float*)(base + 131072);
  float* slotsC        = (float*)(base + 196608);
  float* Up0           = (float*)(base + 262144);            // 2 MiB (32 partials)
  float* U1            = (float*)(base + 2359296);           // 1 MiB
  float* U2            = (float*)(base + 3407872);           // 1 MiB
  float* Sp0           = (float*)(base + 4456448);           // 32 KiB
  float* S1            = (float*)(base + 4489216);           // 16 KiB
  float* S2            = (float*)(base + 4505600);           // 16 KiB
  unsigned short* wkb  = (unsigned short*)(base + 4521984);  // 16 KiB
  unsigned short* wvb  = (unsigned short*)(base + 4538368);  // 16 KiB
  unsigned short* wall = (unsigned short*)(base + 4554752);  // 88 KiB
  unsigned short* qk2g = (unsigned short*)(base + 4644864);  // 128 KiB
  float* outp          = (float*)d_out;

  hipLaunchKernelGGL(k_wpack2, dim3(76), dim3(256), 0, stream,
                     Wk, Wv, wih, whh, w1, w2, Wq, wkb, wvb, wall,
                     noise, mu, lsg, gsl, bsl, slotsA, qws, qk2g);
  hipLaunchKernelGGL(k_lnkv8, dim3(1024), dim3(256), 0, stream,
                     x, wkb, wvb, ling, linb, kg, vt, qk2g, Up0, Sp0);
  // it=1: gru(sum 32-partial Up0/Sp0, slotsA)->slotsB + q; partials -> U1/S1
  hipLaunchKernelGGL(k_attn3, dim3(512), dim3(256), 0, stream,
                     kg, vt, wall, bih, bhh, b1p, b2p, gmlp, bmlp, gsl, bsl,
                     Up0, Sp0, U1, S1, slotsA, slotsB, 32);
  // it=2: gru(sum U1/S1, slotsB)->slotsC + q; partials -> U2/S2
  hipLaunchKernelGGL(k_attn3, dim3(512), dim3(256), 0, stream,
                     kg, vt, wall, bih, bhh, b1p, b2p, gmlp, bmlp, gsl, bsl,
                     U1, S1, U2, S2, slotsB, slotsC, 16);
  // final gru(sum U2/S2, slotsC) -> outp
  hipLaunchKernelGGL(k_gru2, dim3(16), dim3(256), 0, stream, U2, S2, slotsC,
                     wih, whh, bih, bhh, w1, b1p, w2, b2p, gmlp, bmlp, outp);
  (void)in_sizes; (void)n_in; (void)out_size; (void)ws_size;
}

// Round 14
// 198.354 us; speedup vs baseline: 1.0703x; 1.0703x over previous
//
#include <hip/hip_runtime.h>

typedef __attribute__((ext_vector_type(8))) short s16x8;
typedef __attribute__((ext_vector_type(4))) float f32x4;

#define DEV static __device__ __forceinline__

DEV float b2f(unsigned short u){
  unsigned int i = ((unsigned int)u) << 16;
  float f; __builtin_memcpy(&f, &i, 4); return f;
}
DEV unsigned short f2b(float f){
  unsigned int i; __builtin_memcpy(&i, &f, 4);
  i = i + 0x7fffu + ((i >> 16) & 1u);
  return (unsigned short)(i >> 16);
}
DEV f32x4 mfma16(s16x8 a, s16x8 b, f32x4 c){
  return __builtin_amdgcn_mfma_f32_16x16x32_bf16(a, b, c, 0, 0, 0);
}
// load 8 consecutive f32 (32B-aligned) -> bf16 A/B fragment
DEV s16x8 ld8f(const float* p){
  const float4* q4 = (const float4*)p;
  float4 a = q4[0], b = q4[1];
  s16x8 r;
  r[0]=(short)f2b(a.x); r[1]=(short)f2b(a.y); r[2]=(short)f2b(a.z); r[3]=(short)f2b(a.w);
  r[4]=(short)f2b(b.x); r[5]=(short)f2b(b.y); r[6]=(short)f2b(b.z); r[7]=(short)f2b(b.w);
  return r;
}

// DPP-based 16-lane all-reduce sum
template<int C> DEV float dpp_addstep(float x){
  int y = __builtin_amdgcn_update_dpp(0, __builtin_bit_cast(int, x), C, 0xF, 0xF, true);
  return x + __builtin_bit_cast(float, y);
}
DEV float rsum16(float v){
  v = dpp_addstep<0xB1>(v);   // quad_perm xor1
  v = dpp_addstep<0x4E>(v);   // quad_perm xor2
  v = dpp_addstep<0x141>(v);  // row_half_mirror
  v = dpp_addstep<0x140>(v);  // row_mirror
  return v;
}

// ---------------------------------------------------------------------------
// K0: one-shot pack of ALL weights -> bf16. (Round-9 lesson: do NOT inline
// this into k_lnkv -- conversion code between barrier and stores breaks the
// inter-wave store timing the vt write-merge depends on: 33->93MB writes.)
// wall layout (elements): wih@0 whh@12288 w1@24576 w2@32768 wq@40960.
// ---------------------------------------------------------------------------
__global__ __launch_bounds__(256) void k_wpack(
    const float* __restrict__ Wk, const float* __restrict__ Wv,
    const float* __restrict__ wih, const float* __restrict__ whh,
    const float* __restrict__ w1, const float* __restrict__ w2,
    const float* __restrict__ Wq,
    unsigned short* __restrict__ wkb, unsigned short* __restrict__ wvb,
    unsigned short* __restrict__ wall)
{
  int t = blockIdx.x * 256 + threadIdx.x;
  int off = t * 4;
  const float* src; unsigned short* dst;
  if      (off <  8192){ src = Wk  + off;         dst = wkb  + off; }
  else if (off < 16384){ src = Wv  + off -  8192; dst = wvb  + off - 8192; }
  else if (off < 28672){ src = wih + off - 16384; dst = wall + off - 16384; }
  else if (off < 40960){ src = whh + off - 28672; dst = wall + off - 16384; }
  else if (off < 49152){ src = w1  + off - 40960; dst = wall + off - 16384; }
  else if (off < 57344){ src = w2  + off - 49152; dst = wall + off - 16384; }
  else                 { src = Wq  + off - 57344; dst = wall + off - 16384; }
  float4 v = *(const float4*)src;
  ushort4 o;
  o.x = f2b(v.x); o.y = f2b(v.y); o.z = f2b(v.z); o.w = f2b(v.w);
  *(ushort4*)dst = o;
}

// ---------------------------------------------------------------------------
// K1: LN(x) -> k (plain [b][n][h] bf16), v^T ([b][h][n] bf16). FROZEN
// (round-7/10 verified: FETCH 33MB / WRITE 33MB; prefetch-depth null =>
// structural floor).
// INVARIANT: each wave covers TWO adjacent 16-col vt tiles AND no extra code
// between the barrier and the stores.
// ---------------------------------------------------------------------------
__global__ __launch_bounds__(256, 4) void k_lnkv7(
    const float* __restrict__ x,
    const unsigned short* __restrict__ wkb,
    const unsigned short* __restrict__ wvb,
    const float* __restrict__ lg,
    const float* __restrict__ lb,
    unsigned short* __restrict__ kg,
    unsigned short* __restrict__ vt,
    // init tail-block args
    const float* __restrict__ noise,
    const float* __restrict__ mu,
    const float* __restrict__ lsg,
    const float* __restrict__ gsl,
    const float* __restrict__ bsl,
    const float* __restrict__ Wq,
    float* __restrict__ slots,
    unsigned short* __restrict__ qws)
{
  __shared__ __align__(16) unsigned int xs[128 * 68];
  const int tid = threadIdx.x;
  const int w = tid >> 6, ln = tid & 63;
  const int m16 = ln & 15, q = ln >> 4;

  if (blockIdx.x >= 1024){
    // ---------------- slot-init path (16 tail blocks) ----------------
    unsigned short* st = (unsigned short*)xs;
    float (*redS)[4] = (float(*)[4])((char*)xs + 2304);
    float (*redQ)[4] = (float(*)[4])((char*)xs + 2560);
    const int bi = blockIdx.x - 1024;
    const int r0 = bi * 16;
    const int cw = w*16 + m16;

    float sl[4], s1[4], s2[4];
    #pragma unroll
    for (int rr = 0; rr < 4; ++rr){
      int row = r0 + q*4 + rr;
      int k = row & 7;
      float v = mu[k*64 + cw] + (log1pf(expf(lsg[k*64 + cw])) + 1e-5f) * noise[row*64 + cw];
      sl[rr] = v;
      slots[row*64 + cw] = v;
      s1[rr] = rsum16(v);
      s2[rr] = rsum16(v*v);
    }
    if (m16 == 0){
      #pragma unroll
      for (int rr = 0; rr < 4; ++rr){ redS[q*4+rr][w] = s1[rr]; redQ[q*4+rr][w] = s2[rr]; }
    }
    __syncthreads();
    {
      const float gs = gsl[cw], bs = bsl[cw];
      #pragma unroll
      for (int rr = 0; rr < 4; ++rr){
        f32x4 aS = *(const f32x4*)redS[q*4+rr];
        f32x4 aQ = *(const f32x4*)redQ[q*4+rr];
        float tS = aS[0]+aS[1]+aS[2]+aS[3];
        float tQ = aQ[0]+aQ[1]+aQ[2]+aQ[3];
        float mean = tS*(1.f/64.f);
        float var  = tQ*(1.f/64.f) - mean*mean;
        float rs = rsqrtf(var + 1e-5f);
        float sq = (sl[rr] - mean)*rs*gs + bs;
        st[(q*4+rr)*72 + cw] = f2b(sq);
      }
    }
    __syncthreads();
    {
      f32x4 acc = {0,0,0,0};
      #pragma unroll
      for (int ks = 0; ks < 2; ++ks){
        s16x8 a = *(const s16x8*)(st + m16*72 + ks*32 + q*8);
        acc = mfma16(a, ld8f(Wq + cw*64 + ks*32 + q*8), acc);
      }
      #pragma unroll
      for (int rr = 0; rr < 4; ++rr){
        int row = r0 + q*4 + rr;
        int bb_ = row >> 3, kk = row & 7;
        qws[(bb_*16 + kk)*64 + cw] = f2b(acc[rr] * 0.125f);
      }
      int b0 = bi * 2;
      ((unsigned int*)(qws + (b0*16 + 8)*64))[tid] = 0u;
      ((unsigned int*)(qws + ((b0+1)*16 + 8)*64))[tid] = 0u;
    }
    return;
  }

  // ---------------- LN + KV path (1024 blocks, 128 rows each) -------------
  const int b = blockIdx.x >> 5;
  const int nbase = (blockIdx.x & 31) << 7;
  const long rowg0 = (long)b * 4096 + nbase;

  {
    const int c = m16;
    const float4 gA = *(const float4*)(lg + c*4);
    const float4 gB = *(const float4*)(lg + 64 + c*4);
    const float4 bA = *(const float4*)(lb + c*4);
    const float4 bB = *(const float4*)(lb + 64 + c*4);
    const float* base = x + (rowg0 + w*32 + q)*128;

    float4 va[4], vb[4];
    #pragma unroll
    for (int i = 0; i < 3; ++i){
      va[i] = *(const float4*)(base + i*512 + c*4);
      vb[i] = *(const float4*)(base + i*512 + 64 + c*4);
    }
    #pragma unroll
    for (int p = 0; p < 8; ++p){
      const int cur = p & 3;
      if (p < 5){
        const int nxt = (p+3) & 3;
        va[nxt] = *(const float4*)(base + (p+3)*512 + c*4);
        vb[nxt] = *(const float4*)(base + (p+3)*512 + 64 + c*4);
      }
      float4 u = va[cur], t = vb[cur];
      float s1 = (u.x + u.y) + (u.z + u.w) + (t.x + t.y) + (t.z + t.w);
      float s2 = (u.x*u.x + u.y*u.y) + (u.z*u.z + u.w*u.w)
               + (t.x*t.x + t.y*t.y) + (t.z*t.z + t.w*t.w);
      s1 = rsum16(s1);
      s2 = rsum16(s2);
      float mean = s1 * (1.f/128.f);
      float var  = s2 * (1.f/128.f) - mean*mean;
      float rs = rsqrtf(var + 1e-5f);
      float y0 = (u.x - mean)*rs*gA.x + bA.x;
      float y1 = (u.y - mean)*rs*gA.y + bA.y;
      float y2 = (u.z - mean)*rs*gA.z + bA.z;
      float y3 = (u.w - mean)*rs*gA.w + bA.w;
      float y4 = (t.x - mean)*rs*gB.x + bB.x;
      float y5 = (t.y - mean)*rs*gB.y + bB.y;
      float y6 = (t.z - mean)*rs*gB.z + bB.z;
      float y7 = (t.w - mean)*rs*gB.w + bB.w;
      uint2 pkA, pkB;
      pkA.x = (unsigned int)f2b(y0) | ((unsigned int)f2b(y1) << 16);
      pkA.y = (unsigned int)f2b(y2) | ((unsigned int)f2b(y3) << 16);
      pkB.x = (unsigned int)f2b(y4) | ((unsigned int)f2b(y5) << 16);
      pkB.y = (unsigned int)f2b(y6) | ((unsigned int)f2b(y7) << 16);
      const int r = w*32 + p*4 + q;
      *(uint2*)&xs[r*68 + c*2] = pkA;
      *(uint2*)&xs[r*68 + 32 + c*2] = pkB;
    }
  }

  s16x8 bw[4][4];
  #pragma unroll
  for (int t = 0; t < 4; ++t)
    #pragma unroll
    for (int kb = 0; kb < 4; ++kb)
      bw[kb][t] = *(const s16x8*)(wkb + (t*16 + m16)*128 + kb*32 + q*8);

  __syncthreads();

  const f32x4 zf = {0.f, 0.f, 0.f, 0.f};

  #pragma unroll
  for (int mi = 0; mi < 2; ++mi){
    int n0 = (w*2 + mi) * 16;
    f32x4 acc[4];
    #pragma unroll
    for (int t = 0; t < 4; ++t) acc[t] = zf;
    #pragma unroll
    for (int kb = 0; kb < 4; ++kb){
      s16x8 af = *(const s16x8*)((const unsigned short*)(xs + (n0 + m16)*68) + kb*32 + q*8);
      #pragma unroll
      for (int t = 0; t < 4; ++t)
        acc[t] = mfma16(af, bw[kb][t], acc[t]);
    }
    #pragma unroll
    for (int t = 0; t < 4; ++t){
      int h = t*16 + m16;
      #pragma unroll
      for (int rr = 0; rr < 4; ++rr){
        long n = rowg0 + n0 + q*4 + rr;
        kg[n*64 + h] = f2b(acc[t][rr]);
      }
    }
  }

  #pragma unroll
  for (int t = 0; t < 4; ++t)
    #pragma unroll
    for (int kb = 0; kb < 4; ++kb)
      bw[kb][t] = *(const s16x8*)(wvb + (t*16 + m16)*128 + kb*32 + q*8);

  #pragma unroll
  for (int mi = 0; mi < 2; ++mi){
    int n0 = (w*2 + mi) * 16;
    f32x4 acc[4];
    #pragma unroll
    for (int t = 0; t < 4; ++t) acc[t] = zf;
    #pragma unroll
    for (int kb = 0; kb < 4; ++kb){
      s16x8 af = *(const s16x8*)((const unsigned short*)(xs + (n0 + m16)*68) + kb*32 + q*8);
      #pragma unroll
      for (int t = 0; t < 4; ++t)
        acc[t] = mfma16(af, bw[kb][t], acc[t]);
    }
    #pragma unroll
    for (int t = 0; t < 4; ++t){
      int h = t*16 + m16;
      unsigned int p0 = (unsigned int)f2b(acc[t][0]) | ((unsigned int)f2b(acc[t][1]) << 16);
      unsigned int p1 = (unsigned int)f2b(acc[t][2]) | ((unsigned int)f2b(acc[t][3]) << 16);
      uint2 pv; pv.x = p0; pv.y = p1;
      long off = ((long)b*64 + h)*4096 + nbase + n0 + q*4;
      *(uint2*)(vt + off) = pv;
    }
  }
}

// ---------------------------------------------------------------------------
// K3: [GRU prologue (it>0, sums 16 U/S tile-partials)] + attention.
// XCD-aware block swizzle (round-11): pure bijective remap of blockIdx;
// body byte-identical to the verified round-7 k_attn3.
// ---------------------------------------------------------------------------
__global__ __launch_bounds__(256) void k_attn3(
    const unsigned short* __restrict__ kg,
    const unsigned short* __restrict__ vt,
    const unsigned short* __restrict__ qws,   // it==0 only
    const unsigned short* __restrict__ wall,  // packed [wih|whh|w1|w2|wq] bf16
    const float* __restrict__ bih, const float* __restrict__ bhh,
    const float* __restrict__ b1p, const float* __restrict__ b2p,
    const float* __restrict__ gmlp, const float* __restrict__ bmlp,
    const float* __restrict__ gsl, const float* __restrict__ bsl,
    const float* __restrict__ Up_in, const float* __restrict__ Sp_in,
    float* __restrict__ Up_out, float* __restrict__ Sp_out,
    const float* __restrict__ slin, float* __restrict__ slout,
    int it)
{
  __shared__ float sc[256*17];
  __shared__ unsigned short aT[16*264];
  __shared__ unsigned short ut[16*72], ht[16*72], st[16*72], hid[16*136];
  __shared__ unsigned short qloc[16*72];
  __shared__ __align__(16) float redS[16][4];
  __shared__ __align__(16) float redQ[16][4];
  __shared__ __align__(16) float redS2[16][4];
  __shared__ __align__(16) float redQ2[16][4];

  const int tid = threadIdx.x;
  const int w = tid >> 6, ln = tid & 63;
  const int m16 = ln & 15, q = ln >> 4;

  const int p_   = blockIdx.x;
  const int xcd  = p_ & 7;
  const int slot = p_ >> 3;
  const int lb   = ((xcd << 1) + (slot >> 5))*32 + (slot & 31);
  const int b = lb >> 4;
  const int tile = lb & 15;
  const int nbase = tile << 8;

  // ---- prefetch attention operands (independent of prologue) ----
  s16x8 afp[4];
  #pragma unroll
  for (int mi = 0; mi < 4; ++mi){
    int n0 = (w*4 + mi)*16;
    afp[mi] = *(const s16x8*)(kg + ((long)b*4096 + nbase + n0 + m16)*64 + q*8);
  }
  s16x8 afp2[4];
  #pragma unroll
  for (int mi = 0; mi < 4; ++mi){
    int n0 = (w*4 + mi)*16;
    afp2[mi] = *(const s16x8*)(kg + ((long)b*4096 + nbase + n0 + m16)*64 + 32 + q*8);
  }
  s16x8 vtp[8];
  #pragma unroll
  for (int ks = 0; ks < 8; ++ks)
    vtp[ks] = *(const s16x8*)(vt + ((long)b*64 + w*16 + m16)*4096 + nbase + ks*32 + q*8);

  for (int i = tid; i < 8*264; i += 256) aT[8*264 + i] = 0;  // aT slot-pad rows
  if (tid < 128){                                            // qloc pad rows 8..15
    int row = 8 + (tid >> 4), c = (tid & 15)*4;
    ushort4 z4 = {0,0,0,0};
    *(ushort4*)&qloc[row*72 + c] = z4;
  }

  if (it == 0){
    if (tid < 128){
      int row = tid >> 4, c = (tid & 15)*4;
      *(ushort4*)&qloc[row*72 + c] = *(const ushort4*)(qws + (b*16 + row)*64 + c);
    }
  } else {
    // ---- redundant GRU+LN+MLP+LN_sl+q for batch pair (b&~1, b|1) ----
    const int r0 = (b >> 1) * 16;
    const int cw = w*16 + m16;
    const unsigned short* wihb = wall;
    const unsigned short* whhb = wall + 12288;
    const unsigned short* w1b  = wall + 24576;
    const unsigned short* w2b  = wall + 32768;
    const unsigned short* wqb  = wall + 40960;

    #pragma unroll
    for (int p = 0; p < 4; ++p){
      int row = p*4 + w;
      int g = r0 + row;
      int bb = g >> 3, sl = g & 7;
      const float* up  = Up_in + ((bb*16)*8 + sl)*64 + ln;
      const float* spp = Sp_in + (bb*16)*8 + sl;
      float usum = 0.f, ssum = 0.f;
      #pragma unroll
      for (int t = 0; t < 16; ++t){
        usum += up[t*512];
        ssum += spp[t*8];
      }
      ut[row*72 + ln] = f2b(usum / ssum);
      ht[row*72 + ln] = f2b(slin[g*64 + ln]);
    }
    __syncthreads();

    f32x4 axr = {0,0,0,0}, axz = {0,0,0,0}, axn = {0,0,0,0};
    f32x4 ahr = {0,0,0,0}, ahz = {0,0,0,0}, ahn = {0,0,0,0};
    #pragma unroll
    for (int ks = 0; ks < 2; ++ks){
      s16x8 au = *(const s16x8*)(ut + m16*72 + ks*32 + q*8);
      s16x8 ah = *(const s16x8*)(ht + m16*72 + ks*32 + q*8);
      axr = mfma16(au, *(const s16x8*)(wihb + (      cw)*64 + ks*32 + q*8), axr);
      axz = mfma16(au, *(const s16x8*)(wihb + ( 64 + cw)*64 + ks*32 + q*8), axz);
      axn = mfma16(au, *(const s16x8*)(wihb + (128 + cw)*64 + ks*32 + q*8), axn);
      ahr = mfma16(ah, *(const s16x8*)(whhb + (      cw)*64 + ks*32 + q*8), ahr);
      ahz = mfma16(ah, *(const s16x8*)(whhb + ( 64 + cw)*64 + ks*32 + q*8), ahz);
      ahn = mfma16(ah, *(const s16x8*)(whhb + (128 + cw)*64 + ks*32 + q*8), ahn);
    }
    const float bxr = bih[cw], bxz = bih[64+cw], bxn = bih[128+cw];
    const float bhr = bhh[cw], bhz = bhh[64+cw], bhn = bhh[128+cw];
    float sp[4];
    #pragma unroll
    for (int rr = 0; rr < 4; ++rr){
      float xr = axr[rr] + bxr, xz = axz[rr] + bxz, xnv = axn[rr] + bxn;
      float hr = ahr[rr] + bhr, hz = ahz[rr] + bhz, hn = ahn[rr] + bhn;
      float rg = 1.f / (1.f + expf(-(xr + hr)));
      float zg = 1.f / (1.f + expf(-(xz + hz)));
      float ng = tanhf(xnv + rg*hn);
      float hv = b2f(ht[(q*4 + rr)*72 + cw]);
      sp[rr] = (1.f - zg)*ng + zg*hv;
    }

    float s1[4], s2[4];
    #pragma unroll
    for (int rr = 0; rr < 4; ++rr){
      s1[rr] = rsum16(sp[rr]);
      s2[rr] = rsum16(sp[rr]*sp[rr]);
    }
    if (m16 == 0){
      #pragma unroll
      for (int rr = 0; rr < 4; ++rr){ redS[q*4+rr][w] = s1[rr]; redQ[q*4+rr][w] = s2[rr]; }
    }
    __syncthreads();
    float sl_[4];
    {
      const float gm = gmlp[cw], bm = bmlp[cw];
      #pragma unroll
      for (int rr = 0; rr < 4; ++rr){
        f32x4 aS = *(const f32x4*)redS[q*4+rr];
        f32x4 aQ = *(const f32x4*)redQ[q*4+rr];
        float tS = aS[0]+aS[1]+aS[2]+aS[3];
        float tQ = aQ[0]+aQ[1]+aQ[2]+aQ[3];
        float mean = tS*(1.f/64.f);
        float var  = tQ*(1.f/64.f) - mean*mean;
        float rs = rsqrtf(var + 1e-5f);
        sl_[rr] = (sp[rr] - mean)*rs*gm + bm;
        st[(q*4+rr)*72 + cw] = f2b(sl_[rr]);
      }
    }
    __syncthreads();

    // mlp1 (64->128) + relu
    #pragma unroll
    for (int t2 = 0; t2 < 2; ++t2){
      int nt = w*2 + t2;
      int col = nt*16 + m16;
      f32x4 acc = {0,0,0,0};
      #pragma unroll
      for (int ks = 0; ks < 2; ++ks){
        s16x8 a = *(const s16x8*)(st + m16*72 + ks*32 + q*8);
        acc = mfma16(a, *(const s16x8*)(w1b + col*64 + ks*32 + q*8), acc);
      }
      float bb = b1p[col];
      #pragma unroll
      for (int rr = 0; rr < 4; ++rr)
        hid[(q*4+rr)*136 + col] = f2b(fmaxf(acc[rr] + bb, 0.f));
    }
    __syncthreads();

    // mlp2 (128->64) + residual
    float snew[4];
    {
      f32x4 acc = {0,0,0,0};
      #pragma unroll
      for (int ks = 0; ks < 4; ++ks){
        s16x8 a = *(const s16x8*)(hid + m16*136 + ks*32 + q*8);
        acc = mfma16(a, *(const s16x8*)(w2b + cw*128 + ks*32 + q*8), acc);
      }
      float bb = b2p[cw];
      #pragma unroll
      for (int rr = 0; rr < 4; ++rr){
        snew[rr] = sl_[rr] + acc[rr] + bb;
        if ((lb & 31) == 0)
          slout[(r0 + q*4 + rr)*64 + cw] = snew[rr];   // one gate block per pair
      }
    }

    // LN_sl(snew) -> q into qloc (own redS2/redQ2: no pre-write barrier)
    #pragma unroll
    for (int rr = 0; rr < 4; ++rr){
      s1[rr] = rsum16(snew[rr]);
      s2[rr] = rsum16(snew[rr]*snew[rr]);
    }
    if (m16 == 0){
      #pragma unroll
      for (int rr = 0; rr < 4; ++rr){ redS2[q*4+rr][w] = s1[rr]; redQ2[q*4+rr][w] = s2[rr]; }
    }
    __syncthreads();
    {
      const float gs = gsl[cw], bs = bsl[cw];
      #pragma unroll
      for (int rr = 0; rr < 4; ++rr){
        f32x4 aS = *(const f32x4*)redS2[q*4+rr];
        f32x4 aQ = *(const f32x4*)redQ2[q*4+rr];
        float tS = aS[0]+aS[1]+aS[2]+aS[3];
        float tQ = aQ[0]+aQ[1]+aQ[2]+aQ[3];
        float mean = tS*(1.f/64.f);
        float var  = tQ*(1.f/64.f) - mean*mean;
        float rs = rsqrtf(var + 1e-5f);
        float sq = (snew[rr] - mean)*rs*gs + bs;
        st[(q*4+rr)*72 + cw] = f2b(sq);
      }
    }
    __syncthreads();
    {
      f32x4 acc = {0,0,0,0};
      #pragma unroll
      for (int ks = 0; ks < 2; ++ks){
        s16x8 a = *(const s16x8*)(st + m16*72 + ks*32 + q*8);
        acc = mfma16(a, *(const s16x8*)(wqb + cw*64 + ks*32 + q*8), acc);
      }
      #pragma unroll
      for (int rr = 0; rr < 4; ++rr){
        int rloc = q*4 + rr;
        if ((rloc >> 3) == (b & 1))
          qloc[(rloc & 7)*72 + cw] = f2b(acc[rr] * 0.125f);
      }
    }
  }
  __syncthreads();

  // ---- attention (kg already in afp/afp2 registers) ----
  s16x8 bq[2];
  #pragma unroll
  for (int ks = 0; ks < 2; ++ks)
    bq[ks] = *(const s16x8*)(qloc + m16*72 + ks*32 + q*8);

  #pragma unroll
  for (int mi = 0; mi < 4; ++mi){
    int n0 = (w*4 + mi)*16;
    f32x4 acc = {0.f, 0.f, 0.f, 0.f};
    acc = mfma16(afp[mi],  bq[0], acc);
    acc = mfma16(afp2[mi], bq[1], acc);
    #pragma unroll
    for (int rr = 0; rr < 4; ++rr)
      sc[(n0 + q*4 + rr)*17 + m16] = acc[rr];
  }
  __syncthreads();

  {
    int r = tid;
    float a8[8];
    float mx = -1e30f;
    #pragma unroll
    for (int j = 0; j < 8; ++j){ a8[j] = sc[r*17 + j]; mx = fmaxf(mx, a8[j]); }
    float ssum = 0.f;
    #pragma unroll
    for (int j = 0; j < 8; ++j){ a8[j] = expf(a8[j] - mx); ssum += a8[j]; }
    float inv = 1.f/ssum;
    #pragma unroll
    for (int j = 0; j < 8; ++j)
      aT[j*264 + r] = f2b(a8[j]*inv + 1e-8f);
  }
  __syncthreads();

  {  // S tile-partials: rsum16 + one xor16 (reduce over 32 lanes)
    int j = tid >> 5, c = tid & 31;
    float p = 0.f;
    #pragma unroll
    for (int i = 0; i < 8; ++i) p += b2f(aT[j*264 + c + 32*i]);
    p = rsum16(p);
    p += __shfl_xor(p, 16);
    if ((tid & 31) == 0) Sp_out[(b*16 + tile)*8 + j] = p;
  }

  {  // U tile-partials: wave w handles h-tile nt = w; vt already in vtp regs
    f32x4 acc = {0.f, 0.f, 0.f, 0.f};
    #pragma unroll
    for (int ks = 0; ks < 8; ++ks){
      s16x8 af = *(const s16x8*)(aT + m16*264 + ks*32 + q*8);
      acc = mfma16(af, vtp[ks], acc);
    }
    float* ub = Up_out + ((b*16 + tile)*8)*64 + w*16 + m16;
    #pragma unroll
    for (int rr = 0; rr < 4; ++rr){
      int slot2 = q*4 + rr;
      if (slot2 < 8)
        ub[slot2*64] = acc[rr];
    }
  }
}

// ---------------------------------------------------------------------------
// K4: final GRU + LN_mlp + MLP(+residual) -> outp; sums the 16 tile-partials.
// UNCHANGED from round 7.
// ---------------------------------------------------------------------------
__global__ __launch_bounds__(256) void k_gru2(
    const float* __restrict__ Up, const float* __restrict__ Sp,
    const float* __restrict__ slots,
    const float* __restrict__ wih, const float* __restrict__ whh,
    const float* __restrict__ bih, const float* __restrict__ bhh,
    const float* __restrict__ w1, const float* __restrict__ b1p,
    const float* __restrict__ w2, const float* __restrict__ b2p,
    const float* __restrict__ gmlp, const float* __restrict__ bmlp,
    float* __restrict__ outp)
{
  __shared__ unsigned short ut[16*72], ht[16*72], st[16*72], hid[16*136];
  __shared__ __align__(16) float redS[16][4];
  __shared__ __align__(16) float redQ[16][4];
  const int tid = threadIdx.x;
  const int w = tid >> 6, ln = tid & 63;
  const int m16 = ln & 15, q = ln >> 4;
  const int r0 = blockIdx.x * 16;
  const int cw = w*16 + m16;

  #pragma unroll
  for (int p = 0; p < 4; ++p){
    int row = p*4 + w;
    int g = r0 + row;
    int bb = g >> 3, sl = g & 7;
    const float* up  = Up + ((bb*16)*8 + sl)*64 + ln;
    const float* spp = Sp + (bb*16)*8 + sl;
    float usum = 0.f, ssum = 0.f;
    #pragma unroll
    for (int t = 0; t < 16; ++t){
      usum += up[t*512];
      ssum += spp[t*8];
    }
    ut[row*72 + ln] = f2b(usum / ssum);
    ht[row*72 + ln] = f2b(slots[g*64 + ln]);
  }
  __syncthreads();

  f32x4 axr = {0,0,0,0}, axz = {0,0,0,0}, axn = {0,0,0,0};
  f32x4 ahr = {0,0,0,0}, ahz = {0,0,0,0}, ahn = {0,0,0,0};
  #pragma unroll
  for (int ks = 0; ks < 2; ++ks){
    s16x8 au = *(const s16x8*)(ut + m16*72 + ks*32 + q*8);
    s16x8 ah = *(const s16x8*)(ht + m16*72 + ks*32 + q*8);
    axr = mfma16(au, ld8f(wih + (      cw)*64 + ks*32 + q*8), axr);
    axz = mfma16(au, ld8f(wih + ( 64 + cw)*64 + ks*32 + q*8), axz);
    axn = mfma16(au, ld8f(wih + (128 + cw)*64 + ks*32 + q*8), axn);
    ahr = mfma16(ah, ld8f(whh + (      cw)*64 + ks*32 + q*8), ahr);
    ahz = mfma16(ah, ld8f(whh + ( 64 + cw)*64 + ks*32 + q*8), ahz);
    ahn = mfma16(ah, ld8f(whh + (128 + cw)*64 + ks*32 + q*8), ahn);
  }
  const float bxr = bih[cw], bxz = bih[64+cw], bxn = bih[128+cw];
  const float bhr = bhh[cw], bhz = bhh[64+cw], bhn = bhh[128+cw];
  float sp[4];
  #pragma unroll
  for (int rr = 0; rr < 4; ++rr){
    float xr = axr[rr] + bxr, xz = axz[rr] + bxz, xnv = axn[rr] + bxn;
    float hr = ahr[rr] + bhr, hz = ahz[rr] + bhz, hn = ahn[rr] + bhn;
    float rg = 1.f / (1.f + expf(-(xr + hr)));
    float zg = 1.f / (1.f + expf(-(xz + hz)));
    float ng = tanhf(xnv + rg*hn);
    float hv = b2f(ht[(q*4 + rr)*72 + cw]);
    sp[rr] = (1.f - zg)*ng + zg*hv;
  }

  float s1[4], s2[4];
  #pragma unroll
  for (int rr = 0; rr < 4; ++rr){
    s1[rr] = rsum16(sp[rr]);
    s2[rr] = rsum16(sp[rr]*sp[rr]);
  }
  if (m16 == 0){
    #pragma unroll
    for (int rr = 0; rr < 4; ++rr){ redS[q*4+rr][w] = s1[rr]; redQ[q*4+rr][w] = s2[rr]; }
  }
  __syncthreads();
  float sl_[4];
  {
    const float gm = gmlp[cw], bm = bmlp[cw];
    #pragma unroll
    for (int rr = 0; rr < 4; ++rr){
      f32x4 aS = *(const f32x4*)redS[q*4+rr];
      f32x4 aQ = *(const f32x4*)redQ[q*4+rr];
      float tS = aS[0]+aS[1]+aS[2]+aS[3];
      float tQ = aQ[0]+aQ[1]+aQ[2]+aQ[3];
      float mean = tS*(1.f/64.f);
      float var  = tQ*(1.f/64.f) - mean*mean;
      float rs = rsqrtf(var + 1e-5f);
      sl_[rr] = (sp[rr] - mean)*rs*gm + bm;
      st[(q*4+rr)*72 + cw] = f2b(sl_[rr]);
    }
  }
  __syncthreads();

  #pragma unroll
  for (int t2 = 0; t2 < 2; ++t2){
    int nt = w*2 + t2;
    int col = nt*16 + m16;
    f32x4 acc = {0,0,0,0};
    #pragma unroll
    for (int ks = 0; ks < 2; ++ks){
      s16x8 a = *(const s16x8*)(st + m16*72 + ks*32 + q*8);
      acc = mfma16(a, ld8f(w1 + col*64 + ks*32 + q*8), acc);
    }
    float bb = b1p[col];
    #pragma unroll
    for (int rr = 0; rr < 4; ++rr)
      hid[(q*4+rr)*136 + col] = f2b(fmaxf(acc[rr] + bb, 0.f));
  }
  __syncthreads();

  {
    f32x4 acc = {0,0,0,0};
    #pragma unroll
    for (int ks = 0; ks < 4; ++ks){
      s16x8 a = *(const s16x8*)(hid + m16*136 + ks*32 + q*8);
      acc = mfma16(a, ld8f(w2 + cw*128 + ks*32 + q*8), acc);
    }
    float bb = b2p[cw];
    #pragma unroll
    for (int rr = 0; rr < 4; ++rr){
      int row = r0 + q*4 + rr;
      outp[row*64 + cw] = sl_[rr] + acc[rr] + bb;
    }
  }
}

// ---------------------------------------------------------------------------
extern "C" void kernel_launch(void* const* d_in, const int* in_sizes, int n_in,
                              void* d_out, int out_size, void* d_ws, size_t ws_size,
                              hipStream_t stream)
{
  const float* x    = (const float*)d_in[0];
  const float* noise= (const float*)d_in[1];
  const float* Wq   = (const float*)d_in[2];
  const float* Wk   = (const float*)d_in[3];
  const float* Wv   = (const float*)d_in[4];
  const float* ling = (const float*)d_in[5];
  const float* linb = (const float*)d_in[6];
  const float* gsl  = (const float*)d_in[7];
  const float* bsl  = (const float*)d_in[8];
  const float* gmlp = (const float*)d_in[9];
  const float* bmlp = (const float*)d_in[10];
  const float* wih  = (const float*)d_in[11];
  const float* whh  = (const float*)d_in[12];
  const float* bih  = (const float*)d_in[13];
  const float* bhh  = (const float*)d_in[14];
  const float* w1   = (const float*)d_in[15];
  const float* b1p  = (const float*)d_in[16];
  const float* w2   = (const float*)d_in[17];
  const float* b2p  = (const float*)d_in[18];
  const float* mu   = (const float*)d_in[19];
  const float* lsg  = (const float*)d_in[20];

  char* ws = (char*)d_ws;
  unsigned short* kg   = (unsigned short*)(ws);              // 16 MiB
  unsigned short* vt   = (unsigned short*)(ws + 16777216);   // 16 MiB
  char* base = ws + 33554432;
  unsigned short* qws  = (unsigned short*)(base);            // 64 KiB
  float* slotsA        = (float*)(base + 65536);             // 64 KiB
  float* slotsB        = (float*)(base + 131072);
  float* slotsC        = (float*)(base + 196608);
  float* UA            = (float*)(base + 262144);            // 1 MiB partials
  float* UB            = (float*)(base + 1310720);           // 1 MiB
  float* SA            = (float*)(base + 2359296);           // 16 KiB
  float* SB            = (float*)(base + 2375680);           // 16 KiB
  unsigned short* wkb  = (unsigned short*)(base + 2392064);  // 16 KiB
  unsigned short* wvb  = (unsigned short*)(base + 2408448);  // 16 KiB
  unsigned short* wall = (unsigned short*)(base + 2424832);  // 88 KiB packed weights
  float* outp          = (float*)d_out;

  hipLaunchKernelGGL(k_wpack, dim3(60), dim3(256), 0, stream,
                     Wk, Wv, wih, whh, w1, w2, Wq, wkb, wvb, wall);
  hipLaunchKernelGGL(k_lnkv7, dim3(1040), dim3(256), 0, stream,
                     x, wkb, wvb, ling, linb, kg, vt,
                     noise, mu, lsg, gsl, bsl, Wq, slotsA, qws);
  // it=0: q from qws; write iter-0 partials into UA/SA
  hipLaunchKernelGGL(k_attn3, dim3(512), dim3(256), 0, stream,
                     kg, vt, qws, wall, bih, bhh, b1p, b2p, gmlp, bmlp, gsl, bsl,
                     UA, SA, UA, SA, slotsA, slotsA, 0);
  // it=1: gru(sum UA/SA, slotsA)->slotsB + q; write iter-1 partials into UB/SB
  hipLaunchKernelGGL(k_attn3, dim3(512), dim3(256), 0, stream,
                     kg, vt, qws, wall, bih, bhh, b1p, b2p, gmlp, bmlp, gsl, bsl,
                     UA, SA, UB, SB, slotsA, slotsB, 1);
  // it=2: gru(sum UB/SB, slotsB)->slotsC + q; write iter-2 partials into UA/SA
  hipLaunchKernelGGL(k_attn3, dim3(512), dim3(256), 0, stream,
                     kg, vt, qws, wall, bih, bhh, b1p, b2p, gmlp, bmlp, gsl, bsl,
                     UB, SB, UA, SA, slotsB, slotsC, 2);
  // final gru(sum UA/SA, slotsC) -> outp
  hipLaunchKernelGGL(k_gru2, dim3(16), dim3(256), 0, stream, UA, SA, slotsC,
                     wih, whh, bih, bhh, w1, b1p, w2, b2p, gmlp, bmlp, outp);
  (void)in_sizes; (void)n_in; (void)out_size; (void)ws_size;
}